// Round 1
// baseline (646.588 us; speedup 1.0000x reference)
//
#include <hip/hip_runtime.h>

#define DD   128
#define KTOT 1024
#define BTOT 131072
#define BQ   64
#define KT   64

// swizzle: element (d, r) of a [128][64] d-major tile stored at column
// ((r>>2) ^ ((d>>2)&15))<<2 | (r&3)  -- keeps float4 reads contiguous,
// spreads transpose-staging writes across banks.
__device__ __forceinline__ int swz(int d, int r) {
    return (((r >> 2) ^ ((d >> 2) & 15)) << 2) | (r & 3);
}

__global__ void vq_precompute(const float* __restrict__ E, const float* __restrict__ ema,
                              float* __restrict__ alpha, float* __restrict__ beta,
                              float* __restrict__ gam) {
    int k = blockIdx.x * blockDim.x + threadIdx.x;
    if (k >= KTOT) return;
    const float4* e4 = reinterpret_cast<const float4*>(E + (size_t)k * DD);
    double ss = 0.0;
    #pragma unroll
    for (int i = 0; i < DD / 4; ++i) {
        float4 v = e4[i];
        ss += (double)v.x * v.x + (double)v.y * v.y + (double)v.z * v.z + (double)v.w * v.w;
    }
    float w = ema[k];
    alpha[k] = w;
    beta[k]  = (float)((double)w * ss);
    gam[k]   = 2.0f * w;
}

__global__ __launch_bounds__(256, 2) void vq_main(
    const float* __restrict__ X, const float* __restrict__ E,
    const float* __restrict__ alpha, const float* __restrict__ beta,
    const float* __restrict__ gam,
    float* __restrict__ outZ, float* __restrict__ outIdx,
    double* __restrict__ lossAcc, int* __restrict__ refCount,
    int* __restrict__ refList, int refCap)
{
    __shared__ float smem[16384];           // 64 KB exactly
    float* As = smem;                       // [128][64] d-major swizzled
    float* Es = smem + 8192;                // [128][64] d-major swizzled

    const int tid = threadIdx.x;
    const int tx = tid & 15, ty = tid >> 4;
    const int row0 = blockIdx.x * BQ;

    // ---- stage A tile (transpose + swizzle) ----
    {
        const float4* X4 = reinterpret_cast<const float4*>(X + (size_t)row0 * DD);
        #pragma unroll
        for (int i = 0; i < 8; ++i) {
            int c = tid + i * 256;
            int r = c >> 5, d4 = c & 31, d0 = d4 << 2;
            float4 v = X4[(size_t)r * 32 + d4];
            As[(d0 + 0) * 64 + swz(d0 + 0, r)] = v.x;
            As[(d0 + 1) * 64 + swz(d0 + 1, r)] = v.y;
            As[(d0 + 2) * 64 + swz(d0 + 2, r)] = v.z;
            As[(d0 + 3) * 64 + swz(d0 + 3, r)] = v.w;
        }
    }
    __syncthreads();

    // ---- per-row ||x||^2 via shuffle (4 threads per row) ----
    float cr[4];
    {
        int r = tid >> 2, q = tid & 3;
        float p = 0.f;
        #pragma unroll
        for (int j = 0; j < 32; ++j) {
            int d = q * 32 + j;
            float v = As[d * 64 + swz(d, r)];
            p = fmaf(v, v, p);
        }
        p += __shfl_xor(p, 1);
        p += __shfl_xor(p, 2);
        #pragma unroll
        for (int i = 0; i < 4; ++i) {
            int rl = 4 * (ty & 3) + i;      // local row within this wave's 16 rows
            cr[i] = __shfl(p, rl * 4);
        }
    }

    float b1[4] = {1e30f, 1e30f, 1e30f, 1e30f};
    float b2[4] = {1e30f, 1e30f, 1e30f, 1e30f};
    int   i1[4] = {0, 0, 0, 0};

    for (int kt = 0; kt < KTOT / KT; ++kt) {
        __syncthreads();                    // previous tile fully consumed
        const float4* E4 = reinterpret_cast<const float4*>(E + (size_t)kt * KT * DD);
        #pragma unroll
        for (int i = 0; i < 8; ++i) {
            int c = tid + i * 256;
            int r = c >> 5, d4 = c & 31, d0 = d4 << 2;
            float4 v = E4[(size_t)r * 32 + d4];
            Es[(d0 + 0) * 64 + swz(d0 + 0, r)] = v.x;
            Es[(d0 + 1) * 64 + swz(d0 + 1, r)] = v.y;
            Es[(d0 + 2) * 64 + swz(d0 + 2, r)] = v.z;
            Es[(d0 + 3) * 64 + swz(d0 + 3, r)] = v.w;
        }
        __syncthreads();

        const int kg0 = kt * KT + tx * 4;
        float4 al = *(const float4*)(alpha + kg0);
        float4 be = *(const float4*)(beta + kg0);
        float4 ga = *(const float4*)(gam + kg0);

        float acc[4][4];
        #pragma unroll
        for (int i = 0; i < 4; ++i)
            #pragma unroll
            for (int j = 0; j < 4; ++j) acc[i][j] = 0.f;

        #pragma unroll 4
        for (int d = 0; d < DD; ++d) {
            int x = (d >> 2) & 15;
            float4 a = *(const float4*)(As + d * 64 + ((ty ^ x) << 2));
            float4 e = *(const float4*)(Es + d * 64 + ((tx ^ x) << 2));
            acc[0][0] = fmaf(a.x, e.x, acc[0][0]);
            acc[0][1] = fmaf(a.x, e.y, acc[0][1]);
            acc[0][2] = fmaf(a.x, e.z, acc[0][2]);
            acc[0][3] = fmaf(a.x, e.w, acc[0][3]);
            acc[1][0] = fmaf(a.y, e.x, acc[1][0]);
            acc[1][1] = fmaf(a.y, e.y, acc[1][1]);
            acc[1][2] = fmaf(a.y, e.z, acc[1][2]);
            acc[1][3] = fmaf(a.y, e.w, acc[1][3]);
            acc[2][0] = fmaf(a.z, e.x, acc[2][0]);
            acc[2][1] = fmaf(a.z, e.y, acc[2][1]);
            acc[2][2] = fmaf(a.z, e.z, acc[2][2]);
            acc[2][3] = fmaf(a.z, e.w, acc[2][3]);
            acc[3][0] = fmaf(a.w, e.x, acc[3][0]);
            acc[3][1] = fmaf(a.w, e.y, acc[3][1]);
            acc[3][2] = fmaf(a.w, e.z, acc[3][2]);
            acc[3][3] = fmaf(a.w, e.w, acc[3][3]);
        }

        float aa[4] = {al.x, al.y, al.z, al.w};
        float bb[4] = {be.x, be.y, be.z, be.w};
        float gg[4] = {ga.x, ga.y, ga.z, ga.w};
        #pragma unroll
        for (int j = 0; j < 4; ++j) {
            int k = kg0 + j;
            #pragma unroll
            for (int i = 0; i < 4; ++i) {
                float ddv = fmaf(-gg[j], acc[i][j], fmaf(aa[j], cr[i], bb[j]));
                if (ddv < b1[i]) { b2[i] = b1[i]; b1[i] = ddv; i1[i] = k; }
                else if (ddv < b2[i]) b2[i] = ddv;
            }
        }
    }
    __syncthreads();                        // Es no longer needed: overlay reductions

    float* red1 = Es;                       // [64][16]
    float* red2 = Es + 1024;                // [64][16]
    int*   redi = (int*)(Es + 2048);        // [64][16]
    int*   bestS = (int*)(Es + 3072);       // [64]
    double* lred = (double*)(Es + 3136);    // [256] (8B aligned)

    #pragma unroll
    for (int i = 0; i < 4; ++i) {
        int r = ty * 4 + i;
        red1[r * 16 + tx] = b1[i];
        red2[r * 16 + tx] = b2[i];
        redi[r * 16 + tx] = i1[i];
    }
    __syncthreads();

    if (tid < 64) {
        float B1 = 1e30f, B2 = 1e30f; int I1 = KTOT;
        #pragma unroll
        for (int t = 0; t < 16; ++t) {
            float v1 = red1[tid * 16 + t];
            float v2 = red2[tid * 16 + t];
            int   vi = redi[tid * 16 + t];
            if (v1 < B1 || (v1 == B1 && vi < I1)) { B2 = fminf(B1, v2); B1 = v1; I1 = vi; }
            else                                  { B2 = fminf(B2, v1); }
        }
        bestS[tid] = I1;
        outIdx[row0 + tid] = (float)I1;
        // flag near-ties (relative gap < 1e-4) for fp64 refinement
        if (B2 - B1 < 1e-4f * fabsf(B1) + 1e-7f) {
            int p = atomicAdd(refCount, 1);
            if (p < refCap) refList[p] = row0 + tid;
        }
    }
    __syncthreads();

    // ---- gather quantized rows + loss partial ----
    double lp = 0.0;
    for (int c = tid; c < BQ * DD; c += 256) {
        int r = c >> 7, d = c & 127;
        int bi = bestS[r];
        float q = E[(size_t)bi * DD + d];
        float x = As[d * 64 + swz(d, r)];
        outZ[(size_t)(row0 + r) * DD + d] = q;
        float df = q - x;
        lp += (double)df * (double)df;
    }
    lred[tid] = lp;
    __syncthreads();
    for (int s = 128; s > 0; s >>= 1) {
        if (tid < s) lred[tid] += lred[tid + s];
        __syncthreads();
    }
    if (tid == 0) atomicAdd(lossAcc, lred[0]);
}

__global__ void vq_refine(const float* __restrict__ X, const float* __restrict__ E,
                          const float* __restrict__ ema,
                          float* __restrict__ outZ, float* __restrict__ outIdx,
                          double* __restrict__ lossAcc,
                          const int* __restrict__ refCount,
                          const int* __restrict__ refList, int refCap)
{
    __shared__ float xs[DD];
    __shared__ double rb[256];
    __shared__ int    ri[256];
    __shared__ int    s_new, s_old;
    const int tid = threadIdx.x;
    int total = *refCount;
    if (total > refCap) total = refCap;

    for (int it = blockIdx.x; it < total; it += gridDim.x) {
        int row = refList[it];
        __syncthreads();
        if (tid < DD) xs[tid] = X[(size_t)row * DD + tid];
        __syncthreads();

        double lb = 1e300; int li = KTOT;
        #pragma unroll
        for (int j = 0; j < KTOT / 256; ++j) {
            int k = tid + j * 256;
            const float* e = E + (size_t)k * DD;
            double s = 0.0;
            for (int d = 0; d < DD; ++d) {
                double t = (double)xs[d] - (double)e[d];
                s = fma(t, t, s);
            }
            s *= (double)ema[k];
            if (s < lb) { lb = s; li = k; }     // k ascending -> first-min kept
        }
        rb[tid] = lb; ri[tid] = li;
        __syncthreads();
        for (int st = 128; st > 0; st >>= 1) {
            if (tid < st) {
                double ob = rb[tid + st]; int oi = ri[tid + st];
                if (ob < rb[tid] || (ob == rb[tid] && oi < ri[tid])) { rb[tid] = ob; ri[tid] = oi; }
            }
            __syncthreads();
        }
        if (tid == 0) {
            int ni = ri[0];
            int oi = (int)outIdx[row];
            s_new = ni; s_old = oi;
            if (ni != oi) {
                const float* en = E + (size_t)ni * DD;
                const float* eo = E + (size_t)oi * DD;
                double dl = 0.0;
                for (int d = 0; d < DD; ++d) {
                    double dn = (double)en[d] - (double)xs[d];
                    double dod = (double)eo[d] - (double)xs[d];
                    dl += dn * dn - dod * dod;
                }
                atomicAdd(lossAcc, dl);
                outIdx[row] = (float)ni;
            }
        }
        __syncthreads();
        if (s_new != s_old && tid < DD)
            outZ[(size_t)row * DD + tid] = E[(size_t)s_new * DD + tid];
    }
}

__global__ void vq_finalize(const double* __restrict__ lossAcc, float* __restrict__ outLoss) {
    *outLoss = (float)(0.25 * (*lossAcc) / ((double)BTOT * (double)DD));
}

extern "C" void kernel_launch(void* const* d_in, const int* in_sizes, int n_in,
                              void* d_out, int out_size, void* d_ws, size_t ws_size,
                              hipStream_t stream)
{
    const float* X   = (const float*)d_in[0];
    const float* E   = (const float*)d_in[1];
    const float* ema = (const float*)d_in[2];

    float* out     = (float*)d_out;
    float* outZ    = out;
    float* outLoss = out + (size_t)BTOT * DD;
    float* outIdx  = outLoss + 1;

    char* ws = (char*)d_ws;
    double* lossAcc = (double*)ws;            // [0,8)
    int* refCount   = (int*)(ws + 8);         // [8,12)
    float* alpha    = (float*)(ws + 16);
    float* beta     = alpha + KTOT;
    float* gam      = beta + KTOT;
    int* refList    = (int*)(ws + 16 + 3 * KTOT * 4);
    long cap = ((long)ws_size - (16 + 3 * KTOT * 4)) / 4;
    if (cap < 0) cap = 0;
    if (cap > BTOT) cap = BTOT;

    hipMemsetAsync(d_ws, 0, 16, stream);
    vq_precompute<<<dim3(KTOT / 256), dim3(256), 0, stream>>>(E, ema, alpha, beta, gam);
    vq_main<<<dim3(BTOT / BQ), dim3(256), 0, stream>>>(
        X, E, alpha, beta, gam, outZ, outIdx, lossAcc, refCount, refList, (int)cap);
    vq_refine<<<dim3(128), dim3(256), 0, stream>>>(
        X, E, ema, outZ, outIdx, lossAcc, refCount, refList, (int)cap);
    vq_finalize<<<dim3(1), dim3(1), 0, stream>>>(lossAcc, outLoss);
}

// Round 2
// 439.229 us; speedup vs baseline: 1.4721x; 1.4721x over previous
//
#include <hip/hip_runtime.h>

#define DD   128
#define KTOT 1024
#define BTOT 131072

typedef __attribute__((ext_vector_type(8))) short bfrag8;   // 8 bf16 (4 VGPR)
typedef __attribute__((ext_vector_type(4))) float facc4;    // MFMA accumulator

__device__ __forceinline__ unsigned short bf16_rne(float x) {
    unsigned u = __builtin_bit_cast(unsigned, x);
    u += 0x7fffu + ((u >> 16) & 1u);
    return (unsigned short)(u >> 16);
}
__device__ __forceinline__ float bf16f(unsigned short h) {
    unsigned u = ((unsigned)h) << 16;
    return __builtin_bit_cast(float, u);
}

// ---- prep: Eh/El = bf16 split of (2*w*e), alpha = w, beta = w*||e||^2 ----
__global__ void vq_prep(const float* __restrict__ E, const float* __restrict__ ema,
                        unsigned short* __restrict__ Eh, unsigned short* __restrict__ El,
                        float* __restrict__ alpha, float* __restrict__ beta) {
    int k = blockIdx.x * blockDim.x + threadIdx.x;
    if (k >= KTOT) return;
    float w = ema[k];
    alpha[k] = w;
    float tw = 2.0f * w;
    const float* e = E + (size_t)k * DD;
    double ss = 0.0;
    for (int d = 0; d < DD; ++d) {
        float v = e[d];
        ss += (double)v * (double)v;
        float sv = tw * v;
        unsigned short h = bf16_rne(sv);
        Eh[(size_t)k * DD + d] = h;
        El[(size_t)k * DD + d] = bf16_rne(sv - bf16f(h));
    }
    beta[k] = (float)((double)w * ss);
}

// ---- main: MFMA bf16-split distance argmin ----
__global__ __launch_bounds__(256) void vq_mfma(
    const float* __restrict__ X, const float* __restrict__ E,
    const unsigned short* __restrict__ Eh, const unsigned short* __restrict__ El,
    const float* __restrict__ alpha, const float* __restrict__ beta,
    float* __restrict__ outZ, float* __restrict__ outIdx,
    double* __restrict__ lossAcc, int* __restrict__ refCount,
    int* __restrict__ refList, int refCap)
{
    __shared__ int ldsIdx[128];             // 4 waves x 32 rows
    const int tid  = threadIdx.x;
    const int lane = tid & 63, wid = tid >> 6;
    const int g = lane >> 4, m = lane & 15;
    const int rb = blockIdx.x * 128 + wid * 32;

    // ---- X fragments in registers (hi/lo bf16 split) + per-row ||x||^2 ----
    bfrag8 Ah[2][4], Al[2][4];
    float crw[2];
    #pragma unroll
    for (int s = 0; s < 2; ++s) {
        const float* xr = X + (size_t)(rb + s * 16 + m) * DD + g * 8;
        float p = 0.f;
        #pragma unroll
        for (int c = 0; c < 4; ++c) {
            float4 v0 = *(const float4*)(xr + c * 32);
            float4 v1 = *(const float4*)(xr + c * 32 + 4);
            float xs[8] = {v0.x, v0.y, v0.z, v0.w, v1.x, v1.y, v1.z, v1.w};
            #pragma unroll
            for (int j = 0; j < 8; ++j) {
                float x = xs[j];
                p = fmaf(x, x, p);
                unsigned short h = bf16_rne(x);
                Ah[s][c][j] = (short)h;
                Al[s][c][j] = (short)bf16_rne(x - bf16f(h));
            }
        }
        p += __shfl_xor(p, 16);
        p += __shfl_xor(p, 32);
        crw[s] = p;                          // ||x||^2 of row s*16+m (all lanes)
    }
    // cr for this lane's accumulator row-slots: row = s*16 + g*4 + j
    float crs[2][4];
    #pragma unroll
    for (int s = 0; s < 2; ++s)
        #pragma unroll
        for (int j = 0; j < 4; ++j)
            crs[s][j] = __shfl(crw[s], (lane & 48) | (((lane >> 4) & 3) << 2) | j);

    float b1[2][4], b2[2][4];
    int   i1[2][4];
    #pragma unroll
    for (int s = 0; s < 2; ++s)
        #pragma unroll
        for (int j = 0; j < 4; ++j) { b1[s][j] = 3e38f; b2[s][j] = 3e38f; i1[s][j] = 0; }

    const unsigned short* ehp = Eh + (size_t)m * DD + g * 8;
    const unsigned short* elp = El + (size_t)m * DD + g * 8;

    for (int kt = 0; kt < KTOT / 16; ++kt) {
        const int code = (kt << 4) + m;     // this lane's column/code
        bfrag8 Bh[4], Bl[4];
        #pragma unroll
        for (int c = 0; c < 4; ++c) {
            Bh[c] = *(const bfrag8*)(ehp + c * 32);
            Bl[c] = *(const bfrag8*)(elp + c * 32);
        }
        ehp += 16 * DD; elp += 16 * DD;
        float av = alpha[code], bv = beta[code];

        facc4 a0 = {0.f, 0.f, 0.f, 0.f}, a1 = {0.f, 0.f, 0.f, 0.f};
        #pragma unroll
        for (int c = 0; c < 4; ++c) {
            a0 = __builtin_amdgcn_mfma_f32_16x16x32_bf16(Ah[0][c], Bh[c], a0, 0, 0, 0);
            a1 = __builtin_amdgcn_mfma_f32_16x16x32_bf16(Ah[1][c], Bh[c], a1, 0, 0, 0);
        }
        #pragma unroll
        for (int c = 0; c < 4; ++c) {
            a0 = __builtin_amdgcn_mfma_f32_16x16x32_bf16(Ah[0][c], Bl[c], a0, 0, 0, 0);
            a1 = __builtin_amdgcn_mfma_f32_16x16x32_bf16(Ah[1][c], Bl[c], a1, 0, 0, 0);
        }
        #pragma unroll
        for (int c = 0; c < 4; ++c) {
            a0 = __builtin_amdgcn_mfma_f32_16x16x32_bf16(Al[0][c], Bh[c], a0, 0, 0, 0);
            a1 = __builtin_amdgcn_mfma_f32_16x16x32_bf16(Al[1][c], Bh[c], a1, 0, 0, 0);
        }

        #pragma unroll
        for (int j = 0; j < 4; ++j) {
            float d0 = fmaf(av, crs[0][j], bv) - a0[j];
            bool lt0 = d0 < b1[0][j];
            b2[0][j] = fminf(b2[0][j], fmaxf(b1[0][j], d0));
            b1[0][j] = fminf(b1[0][j], d0);
            i1[0][j] = lt0 ? code : i1[0][j];

            float d1 = fmaf(av, crs[1][j], bv) - a1[j];
            bool lt1 = d1 < b1[1][j];
            b2[1][j] = fminf(b2[1][j], fmaxf(b1[1][j], d1));
            b1[1][j] = fminf(b1[1][j], d1);
            i1[1][j] = lt1 ? code : i1[1][j];
        }
    }

    // ---- cross-lane top-2 reduce over the 16 column-lanes (bits 0..3) ----
    for (int off = 1; off < 16; off <<= 1) {
        #pragma unroll
        for (int s = 0; s < 2; ++s)
            #pragma unroll
            for (int j = 0; j < 4; ++j) {
                float ob1 = __shfl_xor(b1[s][j], off);
                float ob2 = __shfl_xor(b2[s][j], off);
                int   oi  = __shfl_xor(i1[s][j], off);
                bool better = (ob1 < b1[s][j]) || (ob1 == b1[s][j] && oi < i1[s][j]);
                float nb2 = better ? fminf(ob2, b1[s][j]) : fminf(b2[s][j], ob1);
                b1[s][j] = better ? ob1 : b1[s][j];
                i1[s][j] = better ? oi  : i1[s][j];
                b2[s][j] = nb2;
            }
    }

    // ---- writers (m==0): idx out, refine flags, loss = sum b1/w ----
    double lsum = 0.0;
    if (m == 0) {
        #pragma unroll
        for (int s = 0; s < 2; ++s)
            #pragma unroll
            for (int j = 0; j < 4; ++j) {
                int row  = rb + s * 16 + g * 4 + j;
                int best = i1[s][j];
                outIdx[row] = (float)best;
                ldsIdx[wid * 32 + s * 16 + g * 4 + j] = best;
                float w = alpha[best];
                lsum += (double)b1[s][j] / (double)w;    // = ||x-q||^2
                float thr = fmaf(4e-4f, b1[s][j], 2e-6f);
                if (b2[s][j] - b1[s][j] < thr) {
                    int p = atomicAdd(refCount, 1);
                    if (p < refCap) refList[p] = row;
                }
            }
    }
    lsum += __shfl_xor(lsum, 16);
    lsum += __shfl_xor(lsum, 32);
    if (lane == 0) atomicAdd(lossAcc, lsum);

    __syncthreads();

    // ---- gather quantized rows: 2 lanes per row, 256 B each ----
    {
        int rl = lane >> 1;
        int best = ldsIdx[wid * 32 + rl];
        const float4* src = (const float4*)(E + (size_t)best * DD + (lane & 1) * 64);
        float4* dst = (float4*)(outZ + (size_t)(rb + rl) * DD + (lane & 1) * 64);
        #pragma unroll
        for (int t = 0; t < 16; ++t) dst[t] = src[t];
    }
}

// ---- fp64 exact re-resolve of flagged rows (proven in round 1) ----
__global__ void vq_refine(const float* __restrict__ X, const float* __restrict__ E,
                          const float* __restrict__ ema,
                          float* __restrict__ outZ, float* __restrict__ outIdx,
                          double* __restrict__ lossAcc,
                          const int* __restrict__ refCount,
                          const int* __restrict__ refList, int refCap)
{
    __shared__ float xs[DD];
    __shared__ double rb[256];
    __shared__ int    ri[256];
    __shared__ int    s_new, s_old;
    const int tid = threadIdx.x;
    int total = *refCount;
    if (total > refCap) total = refCap;

    for (int it = blockIdx.x; it < total; it += gridDim.x) {
        int row = refList[it];
        __syncthreads();
        if (tid < DD) xs[tid] = X[(size_t)row * DD + tid];
        __syncthreads();

        double lb = 1e300; int li = KTOT;
        #pragma unroll
        for (int j = 0; j < KTOT / 256; ++j) {
            int k = tid + j * 256;
            const float* e = E + (size_t)k * DD;
            double s = 0.0;
            for (int d = 0; d < DD; ++d) {
                double t = (double)xs[d] - (double)e[d];
                s = fma(t, t, s);
            }
            s *= (double)ema[k];
            if (s < lb) { lb = s; li = k; }   // ascending k -> first-min kept
        }
        rb[tid] = lb; ri[tid] = li;
        __syncthreads();
        for (int st = 128; st > 0; st >>= 1) {
            if (tid < st) {
                double ob = rb[tid + st]; int oi = ri[tid + st];
                if (ob < rb[tid] || (ob == rb[tid] && oi < ri[tid])) { rb[tid] = ob; ri[tid] = oi; }
            }
            __syncthreads();
        }
        if (tid == 0) {
            int ni = ri[0];
            int oi = (int)outIdx[row];
            s_new = ni; s_old = oi;
            if (ni != oi) {
                const float* en = E + (size_t)ni * DD;
                const float* eo = E + (size_t)oi * DD;
                double dl = 0.0;
                for (int d = 0; d < DD; ++d) {
                    double dn  = (double)en[d] - (double)xs[d];
                    double dod = (double)eo[d] - (double)xs[d];
                    dl += dn * dn - dod * dod;
                }
                atomicAdd(lossAcc, dl);
                outIdx[row] = (float)ni;
            }
        }
        __syncthreads();
        if (s_new != s_old && tid < DD)
            outZ[(size_t)row * DD + tid] = E[(size_t)s_new * DD + tid];
    }
}

__global__ void vq_finalize(const double* __restrict__ lossAcc, float* __restrict__ outLoss) {
    *outLoss = (float)(0.25 * (*lossAcc) / ((double)BTOT * (double)DD));
}

extern "C" void kernel_launch(void* const* d_in, const int* in_sizes, int n_in,
                              void* d_out, int out_size, void* d_ws, size_t ws_size,
                              hipStream_t stream)
{
    const float* X   = (const float*)d_in[0];
    const float* E   = (const float*)d_in[1];
    const float* ema = (const float*)d_in[2];

    float* out     = (float*)d_out;
    float* outZ    = out;
    float* outLoss = out + (size_t)BTOT * DD;
    float* outIdx  = outLoss + 1;

    char* ws = (char*)d_ws;
    double* lossAcc = (double*)ws;                       // [0,8)
    int* refCount   = (int*)(ws + 8);                    // [8,12)
    float* alpha    = (float*)(ws + 16);                 // 4 KB
    float* beta     = (float*)(ws + 16 + 4096);          // 4 KB
    unsigned short* Eh = (unsigned short*)(ws + 8208);   // 256 KB (16B aligned)
    unsigned short* El = (unsigned short*)(ws + 270352); // 256 KB
    int* refList    = (int*)(ws + 532496);
    long cap = ((long)ws_size - 532496) / 4;
    if (cap < 0) cap = 0;
    if (cap > BTOT) cap = BTOT;

    hipMemsetAsync(d_ws, 0, 16, stream);
    vq_prep<<<dim3((KTOT + 255) / 256), dim3(256), 0, stream>>>(E, ema, Eh, El, alpha, beta);
    vq_mfma<<<dim3(BTOT / 128), dim3(256), 0, stream>>>(
        X, E, Eh, El, alpha, beta, outZ, outIdx, lossAcc, refCount, refList, (int)cap);
    vq_refine<<<dim3(128), dim3(256), 0, stream>>>(
        X, E, ema, outZ, outIdx, lossAcc, refCount, refList, (int)cap);
    vq_finalize<<<dim3(1), dim3(1), 0, stream>>>(lossAcc, outLoss);
}

// Round 3
// 275.207 us; speedup vs baseline: 2.3495x; 1.5960x over previous
//
#include <hip/hip_runtime.h>

#define DD    128
#define KTOT  1024
#define BTOT  131072
#define NITER 32            // 32 codes per iteration

typedef __attribute__((ext_vector_type(8))) short bfrag8;   // 8 bf16 (4 VGPR)
typedef __attribute__((ext_vector_type(4))) float facc4;    // MFMA accumulator

__device__ __forceinline__ unsigned short bf16_rne(float x) {
    unsigned u = __builtin_bit_cast(unsigned, x);
    u += 0x7fffu + ((u >> 16) & 1u);
    return (unsigned short)(u >> 16);
}
__device__ __forceinline__ float bf16f(unsigned short h) {
    unsigned u = ((unsigned)h) << 16;
    return __builtin_bit_cast(float, u);
}

__device__ __forceinline__ void gload_lds16(const void* g, void* l) {
    __builtin_amdgcn_global_load_lds(
        (const __attribute__((address_space(1))) void*)g,
        (__attribute__((address_space(3))) void*)l, 16, 0, 0);
}

// ---- prep: Eh/El = bf16 split of (2*w*e), alpha = w, beta = w*||e||^2 ----
__global__ void vq_prep(const float* __restrict__ E, const float* __restrict__ ema,
                        unsigned short* __restrict__ Eh, unsigned short* __restrict__ El,
                        float* __restrict__ alpha, float* __restrict__ beta) {
    int k = blockIdx.x * blockDim.x + threadIdx.x;
    if (k >= KTOT) return;
    float w = ema[k];
    alpha[k] = w;
    float tw = 2.0f * w;
    const float* e = E + (size_t)k * DD;
    double ss = 0.0;
    for (int d = 0; d < DD; ++d) {
        float v = e[d];
        ss += (double)v * (double)v;
        float sv = tw * v;
        unsigned short h = bf16_rne(sv);
        Eh[(size_t)k * DD + d] = h;
        El[(size_t)k * DD + d] = bf16_rne(sv - bf16f(h));
    }
    beta[k] = (float)((double)w * ss);
}

// ---- main: MFMA bf16-split distance argmin, LDS-dbuf B staging ----
__global__ __launch_bounds__(256, 3) void vq_mfma(
    const float* __restrict__ X, const float* __restrict__ E,
    const unsigned short* __restrict__ Eh, const unsigned short* __restrict__ El,
    const float* __restrict__ alpha, const float* __restrict__ beta,
    float* __restrict__ outZ, float* __restrict__ outIdx,
    double* __restrict__ lossAcc, int* __restrict__ refCount,
    int* __restrict__ refList, int refCap)
{
    // LDS: B dbuf [buf:2][hl:2][u:2][m:16][slot:16]x16B = 32 KB, + 128 idx
    __shared__ __align__(128) char smem[33280];
    int* ldsIdx = (int*)(smem + 32768);

    const int tid  = threadIdx.x;
    const int lane = tid & 63, wid = tid >> 6;
    const int g = lane >> 4, m = lane & 15;
    const int rb = blockIdx.x * 128 + wid * 32;

    // ---- staging source pointers (pre-swizzled: chunk = slot ^ row) ----
    const int srow = tid >> 4;                      // 0..15 tile row
    const int schunk = (tid & 15) ^ srow;           // involution
    const unsigned short* pEh = Eh + (size_t)srow * DD + schunk * 8;
    const unsigned short* pEl = El + (size_t)srow * DD + schunk * 8;
    char* ldst0 = smem + wid * 1024;                // wave-uniform dest base

    // ---- prologue: stage tile 0 into buf 0 ----
    #pragma unroll
    for (int u = 0; u < 2; ++u) {
        gload_lds16(pEh + u * 2048, ldst0 + u * 4096);
        gload_lds16(pEl + u * 2048, ldst0 + 8192 + u * 4096);
    }
    pEh += 4096; pEl += 4096;                       // -> tile 1

    // ---- X fragments in registers (hi/lo bf16 split) + per-row ||x||^2 ----
    bfrag8 Ah[2][4], Al[2][4];
    float crw[2];
    #pragma unroll
    for (int s = 0; s < 2; ++s) {
        const float* xr = X + (size_t)(rb + s * 16 + m) * DD + g * 8;
        float p = 0.f;
        #pragma unroll
        for (int c = 0; c < 4; ++c) {
            float4 v0 = *(const float4*)(xr + c * 32);
            float4 v1 = *(const float4*)(xr + c * 32 + 4);
            float xs[8] = {v0.x, v0.y, v0.z, v0.w, v1.x, v1.y, v1.z, v1.w};
            #pragma unroll
            for (int j = 0; j < 8; ++j) {
                float x = xs[j];
                p = fmaf(x, x, p);
                unsigned short h = bf16_rne(x);
                Ah[s][c][j] = (short)h;
                Al[s][c][j] = (short)bf16_rne(x - bf16f(h));
            }
        }
        p += __shfl_xor(p, 16);
        p += __shfl_xor(p, 32);
        crw[s] = p;
    }
    float crs[2][4];
    #pragma unroll
    for (int s = 0; s < 2; ++s)
        #pragma unroll
        for (int j = 0; j < 4; ++j)
            crs[s][j] = __shfl(crw[s], (lane & 48) | (((lane >> 4) & 3) << 2) | j);

    float b1[2][4], b2[2][4];
    int   i1[2][4];
    #pragma unroll
    for (int s = 0; s < 2; ++s)
        #pragma unroll
        for (int j = 0; j < 4; ++j) { b1[s][j] = 3e38f; b2[s][j] = 3e38f; i1[s][j] = 0; }

    // lane-constant swizzled read offsets: slot (g + 4c) ^ m within row m
    int rdofs[4];
    #pragma unroll
    for (int c = 0; c < 4; ++c)
        rdofs[c] = m * 256 + (((g + c * 4) ^ m) << 4);

    __syncthreads();                                // tile 0 staged

    int cur = 0;
    for (int kt = 0; kt < NITER; ++kt) {
        if (kt + 1 < NITER) {                       // stage next tile
            char* nd = smem + ((cur ^ 1) << 14) + wid * 1024;
            #pragma unroll
            for (int u = 0; u < 2; ++u) {
                gload_lds16(pEh + u * 2048, nd + u * 4096);
                gload_lds16(pEl + u * 2048, nd + 8192 + u * 4096);
            }
            pEh += 4096; pEl += 4096;
        }
        const char* bb = smem + (cur << 14);
        #pragma unroll
        for (int u = 0; u < 2; ++u) {
            const int code = kt * 32 + u * 16 + m;
            float av = alpha[code], bv = beta[code];
            bfrag8 Bh[4], Bl[4];
            #pragma unroll
            for (int c = 0; c < 4; ++c) {
                Bh[c] = *(const bfrag8*)(bb + u * 4096 + rdofs[c]);
                Bl[c] = *(const bfrag8*)(bb + 8192 + u * 4096 + rdofs[c]);
            }
            facc4 a0 = {0.f, 0.f, 0.f, 0.f}, a1 = {0.f, 0.f, 0.f, 0.f};
            #pragma unroll
            for (int c = 0; c < 4; ++c) {
                a0 = __builtin_amdgcn_mfma_f32_16x16x32_bf16(Ah[0][c], Bh[c], a0, 0, 0, 0);
                a1 = __builtin_amdgcn_mfma_f32_16x16x32_bf16(Ah[1][c], Bh[c], a1, 0, 0, 0);
            }
            #pragma unroll
            for (int c = 0; c < 4; ++c) {
                a0 = __builtin_amdgcn_mfma_f32_16x16x32_bf16(Ah[0][c], Bl[c], a0, 0, 0, 0);
                a1 = __builtin_amdgcn_mfma_f32_16x16x32_bf16(Ah[1][c], Bl[c], a1, 0, 0, 0);
            }
            #pragma unroll
            for (int c = 0; c < 4; ++c) {
                a0 = __builtin_amdgcn_mfma_f32_16x16x32_bf16(Al[0][c], Bh[c], a0, 0, 0, 0);
                a1 = __builtin_amdgcn_mfma_f32_16x16x32_bf16(Al[1][c], Bh[c], a1, 0, 0, 0);
            }
            #pragma unroll
            for (int j = 0; j < 4; ++j) {
                float d0 = fmaf(av, crs[0][j], bv) - a0[j];
                bool lt0 = d0 < b1[0][j];
                b2[0][j] = fminf(b2[0][j], fmaxf(b1[0][j], d0));
                b1[0][j] = fminf(b1[0][j], d0);
                i1[0][j] = lt0 ? code : i1[0][j];

                float d1 = fmaf(av, crs[1][j], bv) - a1[j];
                bool lt1 = d1 < b1[1][j];
                b2[1][j] = fminf(b2[1][j], fmaxf(b1[1][j], d1));
                b1[1][j] = fminf(b1[1][j], d1);
                i1[1][j] = lt1 ? code : i1[1][j];
            }
        }
        __syncthreads();
        cur ^= 1;
    }

    // ---- cross-lane top-2 reduce over the 16 column-lanes ----
    for (int off = 1; off < 16; off <<= 1) {
        #pragma unroll
        for (int s = 0; s < 2; ++s)
            #pragma unroll
            for (int j = 0; j < 4; ++j) {
                float ob1 = __shfl_xor(b1[s][j], off);
                float ob2 = __shfl_xor(b2[s][j], off);
                int   oi  = __shfl_xor(i1[s][j], off);
                bool better = (ob1 < b1[s][j]) || (ob1 == b1[s][j] && oi < i1[s][j]);
                float nb2 = better ? fminf(ob2, b1[s][j]) : fminf(b2[s][j], ob1);
                b1[s][j] = better ? ob1 : b1[s][j];
                i1[s][j] = better ? oi  : i1[s][j];
                b2[s][j] = nb2;
            }
    }

    // ---- writers (m==0): idx out, refine flags, loss = sum b1/w ----
    double lsum = 0.0;
    if (m == 0) {
        #pragma unroll
        for (int s = 0; s < 2; ++s)
            #pragma unroll
            for (int j = 0; j < 4; ++j) {
                int row  = rb + s * 16 + g * 4 + j;
                int best = i1[s][j];
                outIdx[row] = (float)best;
                ldsIdx[wid * 32 + s * 16 + g * 4 + j] = best;
                float w = alpha[best];
                lsum += (double)b1[s][j] / (double)w;    // = ||x-q||^2
                float thr = fmaf(4e-4f, b1[s][j], 2e-6f);
                if (b2[s][j] - b1[s][j] < thr) {
                    int p = atomicAdd(refCount, 1);
                    if (p < refCap) refList[p] = row;
                }
            }
    }
    lsum += __shfl_xor(lsum, 16);
    lsum += __shfl_xor(lsum, 32);
    if (lane == 0) atomicAdd(lossAcc, lsum);

    __syncthreads();

    // ---- gather quantized rows: 2 lanes per row, 256 B each ----
    {
        int rl = lane >> 1;
        int best = ldsIdx[wid * 32 + rl];
        const float4* src = (const float4*)(E + (size_t)best * DD + (lane & 1) * 64);
        float4* dst = (float4*)(outZ + (size_t)(rb + rl) * DD + (lane & 1) * 64);
        #pragma unroll
        for (int t = 0; t < 16; ++t) dst[t] = src[t];
    }
}

// ---- fp64 exact re-resolve of flagged rows ----
__global__ void vq_refine(const float* __restrict__ X, const float* __restrict__ E,
                          const float* __restrict__ ema,
                          float* __restrict__ outZ, float* __restrict__ outIdx,
                          double* __restrict__ lossAcc,
                          const int* __restrict__ refCount,
                          const int* __restrict__ refList, int refCap)
{
    __shared__ float xs[DD];
    __shared__ double rb[256];
    __shared__ int    ri[256];
    __shared__ int    s_new, s_old;
    const int tid = threadIdx.x;
    int total = *refCount;
    if (total > refCap) total = refCap;

    for (int it = blockIdx.x; it < total; it += gridDim.x) {
        int row = refList[it];
        __syncthreads();
        if (tid < DD) xs[tid] = X[(size_t)row * DD + tid];
        __syncthreads();

        double lb = 1e300; int li = KTOT;
        #pragma unroll
        for (int j = 0; j < KTOT / 256; ++j) {
            int k = tid + j * 256;
            const float* e = E + (size_t)k * DD;
            double s = 0.0;
            for (int d = 0; d < DD; ++d) {
                double t = (double)xs[d] - (double)e[d];
                s = fma(t, t, s);
            }
            s *= (double)ema[k];
            if (s < lb) { lb = s; li = k; }
        }
        rb[tid] = lb; ri[tid] = li;
        __syncthreads();
        for (int st = 128; st > 0; st >>= 1) {
            if (tid < st) {
                double ob = rb[tid + st]; int oi = ri[tid + st];
                if (ob < rb[tid] || (ob == rb[tid] && oi < ri[tid])) { rb[tid] = ob; ri[tid] = oi; }
            }
            __syncthreads();
        }
        if (tid == 0) {
            int ni = ri[0];
            int oi = (int)outIdx[row];
            s_new = ni; s_old = oi;
            if (ni != oi) {
                const float* en = E + (size_t)ni * DD;
                const float* eo = E + (size_t)oi * DD;
                double dl = 0.0;
                for (int d = 0; d < DD; ++d) {
                    double dn  = (double)en[d] - (double)xs[d];
                    double dod = (double)eo[d] - (double)xs[d];
                    dl += dn * dn - dod * dod;
                }
                atomicAdd(lossAcc, dl);
                outIdx[row] = (float)ni;
            }
        }
        __syncthreads();
        if (s_new != s_old && tid < DD)
            outZ[(size_t)row * DD + tid] = E[(size_t)s_new * DD + tid];
    }
}

__global__ void vq_finalize(const double* __restrict__ lossAcc, float* __restrict__ outLoss) {
    *outLoss = (float)(0.25 * (*lossAcc) / ((double)BTOT * (double)DD));
}

extern "C" void kernel_launch(void* const* d_in, const int* in_sizes, int n_in,
                              void* d_out, int out_size, void* d_ws, size_t ws_size,
                              hipStream_t stream)
{
    const float* X   = (const float*)d_in[0];
    const float* E   = (const float*)d_in[1];
    const float* ema = (const float*)d_in[2];

    float* out     = (float*)d_out;
    float* outZ    = out;
    float* outLoss = out + (size_t)BTOT * DD;
    float* outIdx  = outLoss + 1;

    char* ws = (char*)d_ws;
    double* lossAcc = (double*)ws;                       // [0,8)
    int* refCount   = (int*)(ws + 8);                    // [8,12)
    float* alpha    = (float*)(ws + 16);                 // 4 KB
    float* beta     = (float*)(ws + 16 + 4096);          // 4 KB
    unsigned short* Eh = (unsigned short*)(ws + 8208);   // 256 KB (16B aligned)
    unsigned short* El = (unsigned short*)(ws + 270352); // 256 KB
    int* refList    = (int*)(ws + 532496);
    long cap = ((long)ws_size - 532496) / 4;
    if (cap < 0) cap = 0;
    if (cap > BTOT) cap = BTOT;

    hipMemsetAsync(d_ws, 0, 16, stream);
    vq_prep<<<dim3((KTOT + 255) / 256), dim3(256), 0, stream>>>(E, ema, Eh, El, alpha, beta);
    vq_mfma<<<dim3(BTOT / 128), dim3(256), 0, stream>>>(
        X, E, Eh, El, alpha, beta, outZ, outIdx, lossAcc, refCount, refList, (int)cap);
    vq_refine<<<dim3(128), dim3(256), 0, stream>>>(
        X, E, ema, outZ, outIdx, lossAcc, refCount, refList, (int)cap);
    vq_finalize<<<dim3(1), dim3(1), 0, stream>>>(lossAcc, outLoss);
}